// Round 1
// 1021.897 us; speedup vs baseline: 1.1651x; 1.1651x over previous
//
#include <hip/hip_runtime.h>
#include <hip/hip_bf16.h>
#include <cstdio>

typedef unsigned short ushort_t;
using bf16x8  = __attribute__((ext_vector_type(8))) __bf16;
using floatx4 = __attribute__((ext_vector_type(4))) float;

// Problem constants
constexpr int    kTokens = 50176;                       // B*nW*N = 16*64*49
constexpr size_t TCsz    = (size_t)kTokens * 256;       // 12,845,056 elements
constexpr float  kScale  = 0.17677669529663687f;        // 32^-0.5
// Padded score layout: per (win,head) pair, 49 rows x 56 cols (16B-aligned rows)
constexpr int    SPITCH  = 56;
constexpr size_t SPAIR   = 49 * 56;                     // 2744
constexpr size_t SBUFSZ  = (size_t)8192 * SPAIR;        // 22,478,848 halves per branch

__device__ __forceinline__ float bf2f(ushort_t u) {
  unsigned int x = (unsigned int)u << 16;
  return __uint_as_float(x);
}
__device__ __forceinline__ ushort_t f2bf(float f) {
  __hip_bfloat16 h = __float2bfloat16(f);
  return *(ushort_t*)&h;
}

// ---------------- weight fp32 -> bf16 conversion ----------------
__global__ __launch_bounds__(256) void f2b_k(const float* __restrict__ src,
                                             ushort_t* __restrict__ dst, int n) {
  int i = blockIdx.x * 256 + threadIdx.x;
  if (i < n) dst[i] = f2bf(src[i]);
}

// ---------------- precompute rpb + shift-mask bias table ----------------
// bias[cls][head][i][j], cls = (wh==7?2:0)+(ww==7?1:0), 49x56 tile (pad cols = 0)
__global__ __launch_bounds__(256) void bias_k(const float* __restrict__ rpb,
                                              float* __restrict__ bias,
                                              ushort_t* __restrict__ guard) {
  const int cls = blockIdx.x >> 3, head = blockIdx.x & 7;
  const int wh7 = cls >> 1, ww7 = cls & 1;
  float* bp = bias + (size_t)blockIdx.x * SPAIR;
  for (int e = threadIdx.x; e < (int)SPAIR; e += 256) {
    const int i = e / SPITCH, j = e % SPITCH;
    float val = 0.0f;
    if (j < 49) {
      const int yi = i / 7, xi = i % 7, yj = j / 7, xj = j % 7;
      val = rpb[((yi - yj + 6) * 13 + (xi - xj + 6)) * 8 + head];
      const int li = (wh7 ? (yi < 4 ? 1 : 2) : 0) * 3 + (ww7 ? (xi < 4 ? 1 : 2) : 0);
      const int lj = (wh7 ? (yj < 4 ? 1 : 2) : 0) * 3 + (ww7 ? (xj < 4 ? 1 : 2) : 0);
      if (li != lj) val -= 100.0f;
    }
    bp[e] = val;
  }
  if (blockIdx.x == 0 && threadIdx.x < 64) guard[threadIdx.x] = 0;  // NaN guard past SB
}

// ---------------- LN (wave per token) + optional roll/window scatter -> bf16 ----------------
template <int SHIFTED>
__global__ __launch_bounds__(256) void ln_k(const float* __restrict__ x,
                                            const float* __restrict__ g,
                                            const float* __restrict__ b,
                                            ushort_t* __restrict__ yout) {
  const int wave = threadIdx.x >> 6, lane = threadIdx.x & 63;
  const int t = blockIdx.x * 4 + wave;
  size_t src;
  if (SHIFTED) {
    int bb = t / 3136, r = t % 3136;
    int wi = r / 49, n = r % 49;
    int hp = (wi >> 3) * 7 + n / 7;
    int wp = (wi & 7) * 7 + n % 7;
    int sh = hp + 3; if (sh >= 56) sh -= 56;
    int sw = wp + 3; if (sw >= 56) sw -= 56;
    src = ((size_t)bb * 3136 + sh * 56 + sw) * 256;
  } else {
    src = (size_t)t * 256;
  }
  const float4 v4 = *(const float4*)(x + src + lane * 4);
  float s  = v4.x + v4.y + v4.z + v4.w;
  float s2 = v4.x * v4.x + v4.y * v4.y + v4.z * v4.z + v4.w * v4.w;
#pragma unroll
  for (int off = 32; off > 0; off >>= 1) {
    s  += __shfl_xor(s,  off);
    s2 += __shfl_xor(s2, off);
  }
  const float mean = s * (1.0f / 256.0f);
  const float var  = s2 * (1.0f / 256.0f) - mean * mean;
  const float rstd = rsqrtf(var + 1e-5f);
  const float4 g4 = *(const float4*)(g + lane * 4);
  const float4 b4 = *(const float4*)(b + lane * 4);
  ushort4 o;
  o.x = f2bf((v4.x - mean) * rstd * g4.x + b4.x);
  o.y = f2bf((v4.y - mean) * rstd * g4.y + b4.y);
  o.z = f2bf((v4.z - mean) * rstd * g4.z + b4.z);
  o.w = f2bf((v4.w - mean) * rstd * g4.w + b4.w);
  *(ushort4*)(yout + (size_t)t * 256 + lane * 4) = o;
}

// ---------------- bf16 MFMA GEMM: out = A(M x K,bf16) @ W(N x K,bf16)^T ----------------
template <int MODE>
__global__ __launch_bounds__(256) void bgemm_k(const ushort_t* __restrict__ A,
                                               const ushort_t* __restrict__ W,
                                               const float* __restrict__ bias,
                                               float* __restrict__ outf,
                                               ushort_t* __restrict__ outb,
                                               const float* __restrict__ aux,
                                               int K, int Nc) {
  __shared__ __align__(16) ushort_t As[4][128][8];
  __shared__ __align__(16) ushort_t Bs[4][128][8];
  const int tid  = threadIdx.x;
  const int m0   = blockIdx.y * 128;
  const int n0   = blockIdx.x * 128;
  const int lane = tid & 63, wv = tid >> 6;
  const int wm   = (wv >> 1) * 64, wn = (wv & 1) * 64;
  const int l16  = lane & 15, quad = lane >> 4;
  const int srow = tid >> 2;
  const int skc  = tid & 3;

  floatx4 acc[4][4] = {};
  const ushort_t* Ap0 = A + (size_t)(m0 + srow) * K + skc * 8;
  const ushort_t* Ap1 = A + (size_t)(m0 + 64 + srow) * K + skc * 8;
  const ushort_t* Wp0 = W + (size_t)(n0 + srow) * K + skc * 8;
  const ushort_t* Wp1 = W + (size_t)(n0 + 64 + srow) * K + skc * 8;

  for (int k0 = 0; k0 < K; k0 += 32) {
    uint4 a0 = *(const uint4*)(Ap0 + k0);
    uint4 a1 = *(const uint4*)(Ap1 + k0);
    uint4 b0 = *(const uint4*)(Wp0 + k0);
    uint4 b1 = *(const uint4*)(Wp1 + k0);
    *(uint4*)&As[skc][srow][0]      = a0;
    *(uint4*)&As[skc][srow + 64][0] = a1;
    *(uint4*)&Bs[skc][srow][0]      = b0;
    *(uint4*)&Bs[skc][srow + 64][0] = b1;
    __syncthreads();
    bf16x8 af[4], bfr[4];
#pragma unroll
    for (int t = 0; t < 4; ++t) {
      af[t]  = *(const bf16x8*)&As[quad][wm + t * 16 + l16][0];
      bfr[t] = *(const bf16x8*)&Bs[quad][wn + t * 16 + l16][0];
    }
#pragma unroll
    for (int mt = 0; mt < 4; ++mt)
#pragma unroll
      for (int nt = 0; nt < 4; ++nt)
        acc[mt][nt] = __builtin_amdgcn_mfma_f32_16x16x32_bf16(af[mt], bfr[nt], acc[mt][nt], 0, 0, 0);
    __syncthreads();
  }

  // C/D layout: col = lane&15, row = quad*4 + reg
#pragma unroll
  for (int nt = 0; nt < 4; ++nt) {
    const int col = n0 + wn + nt * 16 + l16;
    const float bv = bias[col];
#pragma unroll
    for (int mt = 0; mt < 4; ++mt) {
#pragma unroll
      for (int r = 0; r < 4; ++r) {
        const int row = m0 + wm + mt * 16 + quad * 4 + r;
        float val = acc[mt][nt][r] + bv;
        if (MODE == 0) {
          const int which = col >> 8, head = (col >> 5) & 7, d = col & 31;
          if (which == 0) val *= kScale;
          const int wi = row / 49, n = row % 49;
          outb[(size_t)which * TCsz + (size_t)(wi * 8 + head) * 1568 + n * 32 + d] = f2bf(val);
        } else if (MODE == 1) {
          const int wi = row / 49, n = row % 49;
          const int b = wi >> 6, wl = wi & 63;
          const int hp = (wl >> 3) * 7 + n / 7;
          const int wp = (wl & 7) * 7 + n % 7;
          int h = hp + 3; if (h >= 56) h -= 56;
          int w = wp + 3; if (w >= 56) w -= 56;
          const size_t idx = ((size_t)(b * 3136 + h * 56 + w)) * 256 + col;
          outf[idx] = aux[idx] + val;
        } else if (MODE == 2) {
          val = 0.5f * val * (1.0f + erff(val * 0.70710678118654752f));
          outb[(size_t)row * Nc + col] = f2bf(val);
        } else {
          const size_t idx = (size_t)row * 256 + col;
          outf[idx] = aux[idx] + val;
        }
      }
    }
  }
}

// ---------------- MFMA scores: S = q@k^T + bias(cls,head), one wave per (win,head) ----
// q pre-scaled. S padded [49][56] bf16 per pair; pad cols written as 0.
__global__ __launch_bounds__(256) void scores_mfma_k(const ushort_t* __restrict__ q,
                                                     const ushort_t* __restrict__ k,
                                                     const float* __restrict__ bias,
                                                     ushort_t* __restrict__ S) {
  const int tid = threadIdx.x, lane = tid & 63, wv = tid >> 6;
  const int pair = blockIdx.x * 4 + wv;        // 8192 pairs
  const int head = pair & 7, win = pair >> 3;
  const int l16 = lane & 15, quad = lane >> 4;
  const ushort_t* qb = q + (size_t)pair * 1568;
  const ushort_t* kb = k + (size_t)pair * 1568;
  bf16x8 af[4], bfr[4];
#pragma unroll
  for (int t = 0; t < 4; ++t) {
    af[t]  = *(const bf16x8*)(qb + (t * 16 + l16) * 32 + quad * 8);
    bfr[t] = *(const bf16x8*)(kb + (t * 16 + l16) * 32 + quad * 8);
  }
  floatx4 acc[4][4] = {};
#pragma unroll
  for (int mt = 0; mt < 4; ++mt)
#pragma unroll
    for (int nt = 0; nt < 4; ++nt)
      acc[mt][nt] = __builtin_amdgcn_mfma_f32_16x16x32_bf16(af[mt], bfr[nt], acc[mt][nt], 0, 0, 0);

  const int wl = win & 63;
  const int cls = (((wl >> 3) == 7) ? 2 : 0) + (((wl & 7) == 7) ? 1 : 0);
  const float* bp = bias + (size_t)(cls * 8 + head) * SPAIR;
  ushort_t* Sp = S + (size_t)pair * SPAIR;
#pragma unroll
  for (int nt = 0; nt < 4; ++nt) {
    const int col = nt * 16 + l16;
    if (col >= SPITCH) continue;
#pragma unroll
    for (int mt = 0; mt < 4; ++mt) {
#pragma unroll
      for (int r = 0; r < 4; ++r) {
        const int row = mt * 16 + quad * 4 + r;
        if (row >= 49) continue;
        const float val = (col < 49) ? acc[mt][nt][r] + bp[row * SPITCH + col] : 0.0f;
        Sp[row * SPITCH + col] = f2bf(val);
      }
    }
  }
}

// ---------------- head-fusion gate + softmax, chunked (window, 13-row) blocks ------------
__global__ __launch_bounds__(256) void fuse2_k(ushort_t* __restrict__ S,
                                               ushort_t* __restrict__ Ss,
                                               const float* __restrict__ fw,
                                               const float* __restrict__ fb) {
  __shared__ float s[8][637], ss[8][637];   // 13*49 = 637 ; 40.8 KB total
  __shared__ float fwl[64], fbl[8];
  const int w = blockIdx.x >> 2, ch = blockIdx.x & 3;
  const int n0 = ch * 13;
  const int rows = (n0 + 13 <= 49) ? 13 : (49 - n0);
  const int cnt = 8 * rows * 49;
  const int tid = threadIdx.x;
  if (tid < 64) fwl[tid] = fw[tid];
  if (tid < 8)  fbl[tid] = fb[tid];
  for (int t = tid; t < cnt; t += 256) {
    const int h = t / (rows * 49), rm = t % (rows * 49);
    const int r = rm / 49, c = rm - r * 49;
    const size_t gaddr = (size_t)(w * 8 + h) * SPAIR + (size_t)(n0 + r) * SPITCH + c;
    s[h][rm]  = bf2f(S[gaddr]);
    ss[h][rm] = bf2f(Ss[gaddr]);
  }
  __syncthreads();
  for (int p = tid; p < rows * 49; p += 256) {
    float d[8];
#pragma unroll
    for (int h = 0; h < 8; ++h) d[h] = ss[h][p] - s[h][p];
#pragma unroll
    for (int o = 0; o < 8; ++o) {
      float g = fbl[o];
#pragma unroll
      for (int h = 0; h < 8; ++h) g = fmaf(fwl[o * 8 + h], d[h], g);
      g = 1.0f / (1.0f + expf(-g));
      s[o][p] = s[o][p] + d[o] * g;
    }
  }
  __syncthreads();
  // softmax: one thread per (branch, head, row)
  if (tid < 16 * rows) {
    const int br = tid / (8 * rows);
    const int hr = tid % (8 * rows);
    const int h = hr / rows, r = hr % rows;
    float* row = (br ? ss[h] : s[h]) + r * 49;
    float mx = -1e30f;
    for (int m = 0; m < 49; ++m) mx = fmaxf(mx, row[m]);
    float sum = 0.0f;
    for (int m = 0; m < 49; ++m) { float e = expf(row[m] - mx); row[m] = e; sum += e; }
    const float inv = 1.0f / sum;
    for (int m = 0; m < 49; ++m) row[m] *= inv;
  }
  __syncthreads();
  for (int t = tid; t < cnt; t += 256) {
    const int h = t / (rows * 49), rm = t % (rows * 49);
    const int r = rm / 49, c = rm - r * 49;
    const size_t gaddr = (size_t)(w * 8 + h) * SPAIR + (size_t)(n0 + r) * SPITCH + c;
    S[gaddr]  = f2bf(s[h][rm]);
    Ss[gaddr] = f2bf(ss[h][rm]);
  }
}

// ---------------- MFMA PV: O = P @ V, one wave per (win,head) ----------------
// P read from padded S (stride 56, pad cols = 0). V^T staged in LDS, m-padded with 0.
__global__ __launch_bounds__(256) void pv_mfma_k(const ushort_t* __restrict__ P,
                                                 const ushort_t* __restrict__ v,
                                                 ushort_t* __restrict__ O) {
  __shared__ __align__(16) ushort_t vt[4][32][72];
  const int tid = threadIdx.x, lane = tid & 63, wv = tid >> 6;
  const int pair = blockIdx.x * 4 + wv;
  const int head = pair & 7, win = pair >> 3;
  const int l16 = lane & 15, quad = lane >> 4;
  const ushort_t* vb = v + (size_t)pair * 1568;
  // zero pad: m in [49,72) for all d  (32*23 = 736 elems)
  for (int e = lane; e < 736; e += 64) {
    const int d = e / 23, m = 49 + e % 23;
    vt[wv][d][m] = 0;
  }
  // transpose-stage V: vt[d][m] = v[m][d]
  for (int e = lane; e < 1568; e += 64) {
    vt[wv][e & 31][e >> 5] = vb[e];
  }
  __syncthreads();
  bf16x8 bfr[2][2];
#pragma unroll
  for (int nt = 0; nt < 2; ++nt)
#pragma unroll
    for (int ks = 0; ks < 2; ++ks)
      bfr[nt][ks] = *(const bf16x8*)&vt[wv][nt * 16 + l16][ks * 32 + quad * 8];

  const ushort_t* Pb = P + (size_t)pair * SPAIR;
  floatx4 acc[4][2] = {};
#pragma unroll
  for (int ks = 0; ks < 2; ++ks) {
#pragma unroll
    for (int mt = 0; mt < 4; ++mt) {
      const bf16x8 af = *(const bf16x8*)(Pb + (size_t)(mt * 16 + l16) * SPITCH + ks * 32 + quad * 8);
#pragma unroll
      for (int nt = 0; nt < 2; ++nt)
        acc[mt][nt] = __builtin_amdgcn_mfma_f32_16x16x32_bf16(af, bfr[nt][ks], acc[mt][nt], 0, 0, 0);
    }
  }
#pragma unroll
  for (int mt = 0; mt < 4; ++mt) {
#pragma unroll
    for (int r = 0; r < 4; ++r) {
      const int n = mt * 16 + quad * 4 + r;
      if (n >= 49) continue;
      const size_t base = ((size_t)(win * 49 + n)) * 256 + head * 32;
#pragma unroll
      for (int nt = 0; nt < 2; ++nt)
        O[base + nt * 16 + l16] = f2bf(acc[mt][nt][r]);
    }
  }
}

extern "C" void kernel_launch(void* const* d_in, const int* in_sizes, int n_in,
                              void* d_out, int out_size, void* d_ws, size_t ws_size,
                              hipStream_t stream) {
  if (n_in < 29) { fprintf(stderr, "kernel_launch: expected 29 inputs, got %d\n", n_in); return; }
  const float* x      = (const float*)d_in[0];
  const float* xsar   = (const float*)d_in[1];
  const float* ln1_g  = (const float*)d_in[2];
  const float* ln1_b  = (const float*)d_in[3];
  const float* ln1s_g = (const float*)d_in[4];
  const float* ln1s_b = (const float*)d_in[5];
  const float* qkv_w  = (const float*)d_in[6];
  const float* qkv_b  = (const float*)d_in[7];
  const float* qkvs_w = (const float*)d_in[8];
  const float* qkvs_b = (const float*)d_in[9];
  const float* rpb    = (const float*)d_in[10];
  const float* fuse_w = (const float*)d_in[11];
  const float* fuse_b = (const float*)d_in[12];
  const float* proj_w = (const float*)d_in[13];
  const float* proj_b = (const float*)d_in[14];
  const float* projs_w = (const float*)d_in[15];
  const float* projs_b = (const float*)d_in[16];
  const float* ln2_g  = (const float*)d_in[17];
  const float* ln2_b  = (const float*)d_in[18];
  const float* ln2s_g = (const float*)d_in[19];
  const float* ln2s_b = (const float*)d_in[20];
  const float* fc1_w  = (const float*)d_in[21];
  const float* fc1_b  = (const float*)d_in[22];
  const float* fc2_w  = (const float*)d_in[23];
  const float* fc2_b  = (const float*)d_in[24];
  const float* fc1s_w = (const float*)d_in[25];
  const float* fc1s_b = (const float*)d_in[26];
  const float* fc2s_w = (const float*)d_in[27];
  const float* fc2s_b = (const float*)d_in[28];
  float* out = (float*)d_out;
  float* ws  = (float*)d_ws;

  const size_t need = 8 * TCsz * sizeof(float);
  if (ws_size < need) {
    fprintf(stderr, "kernel_launch: ws_size %zu < needed %zu\n", ws_size, need);
    return;
  }

  // --- All-halves (bf16) workspace map; H unit = 1 bf16, 16*TCsz halves total ---
  // xw[0,1TC) xws[1,2TC) | q[2,3) k[3,4) v[4,5) qs[5,6) ks[6,7) vs[7,8) (TC each)
  // SA [8TC, 8TC+SBUFSZ)  SB [.., +SBUFSZ)  guard[64]
  // bias table fp32 + bf16 weights just below 12TC | xr fp32 [6,7)f  xrs [7,8)f
  // After liveness: O->xw slot, Os->xws, y->q, ys->k, hbuf->[4,8TC)
  ushort_t* H   = (ushort_t*)ws;
  ushort_t* xw  = H;
  ushort_t* xws = H + TCsz;
  ushort_t* q   = H + 2 * TCsz;   // q,k,v contiguous (which*TCsz offsets)
  ushort_t* qs  = H + 5 * TCsz;
  ushort_t* v_  = H + 4 * TCsz;
  ushort_t* vs  = H + 7 * TCsz;
  ushort_t* SA  = H + 8 * TCsz;
  ushort_t* SB  = SA + SBUFSZ;
  ushort_t* guard = SB + SBUFSZ;  // 64 halves zeroed (NaN guard for PV K-tail)
  float* xr  = ws + 6 * TCsz;
  float* xrs = ws + 7 * TCsz;
  ushort_t* y   = H + 2 * TCsz;
  ushort_t* ysb = H + 3 * TCsz;
  ushort_t* hbuf = H + 4 * TCsz;  // 4 TC halves: full M x 1024
  ushort_t* wb  = H + 12 * TCsz - 1572864;  // bf16 weights, below xr region
  float* biasbuf = (float*)(H + 12 * TCsz - 1572864 - 175616);  // 4*8*2744 fp32
  ushort_t* wqkv  = wb;
  ushort_t* wqkvs = wb + 196608;
  ushort_t* wproj = wb + 393216;
  ushort_t* wprojs= wb + 458752;
  ushort_t* wfc1  = wb + 524288;
  ushort_t* wfc1s = wb + 786432;
  ushort_t* wfc2  = wb + 1048576;
  ushort_t* wfc2s = wb + 1310720;

  // 0. convert weights to bf16 + precompute rpb/mask bias table
  f2b_k<<<768, 256, 0, stream>>>(qkv_w,  wqkv,  196608);
  f2b_k<<<768, 256, 0, stream>>>(qkvs_w, wqkvs, 196608);
  f2b_k<<<256, 256, 0, stream>>>(proj_w, wproj, 65536);
  f2b_k<<<256, 256, 0, stream>>>(projs_w,wprojs,65536);
  f2b_k<<<1024,256, 0, stream>>>(fc1_w,  wfc1,  262144);
  f2b_k<<<1024,256, 0, stream>>>(fc1s_w, wfc1s, 262144);
  f2b_k<<<1024,256, 0, stream>>>(fc2_w,  wfc2,  262144);
  f2b_k<<<1024,256, 0, stream>>>(fc2s_w, wfc2s, 262144);
  bias_k<<<32, 256, 0, stream>>>(rpb, biasbuf, guard);

  // 1. LN1 + shift + window partition (bf16 out), wave-per-token
  ln_k<1><<<12544, 256, 0, stream>>>(x,    ln1_g,  ln1_b,  xw);
  ln_k<1><<<12544, 256, 0, stream>>>(xsar, ln1s_g, ln1s_b, xws);
  // 2. QKV MFMA GEMM (q pre-scaled), scatter bf16 to (win,head,n,d)
  bgemm_k<0><<<dim3(6, 392), 256, 0, stream>>>(xw,  wqkv,  qkv_b,  nullptr, q,  nullptr, 256, 768);
  bgemm_k<0><<<dim3(6, 392), 256, 0, stream>>>(xws, wqkvs, qkvs_b, nullptr, qs, nullptr, 256, 768);
  // 3. MFMA scores + precomputed bias (bf16 out, padded 49x56)
  scores_mfma_k<<<2048, 256, 0, stream>>>(q,  q + TCsz,  biasbuf, SA);
  scores_mfma_k<<<2048, 256, 0, stream>>>(qs, qs + TCsz, biasbuf, SB);
  // 4. gate fusion + softmax (in place, chunked; pad cols preserved as 0)
  fuse2_k<<<4096, 256, 0, stream>>>(SA, SB, fuse_w, fuse_b);
  // 5. MFMA P @ V -> bf16 token-major
  pv_mfma_k<<<2048, 256, 0, stream>>>(SA, v_, H);          // O -> xw slot
  pv_mfma_k<<<2048, 256, 0, stream>>>(SB, vs, H + TCsz);   // Os -> xws slot
  // 6. proj MFMA + window-reverse + roll(+3) + residual -> fp32 xr
  bgemm_k<1><<<dim3(2, 392), 256, 0, stream>>>(H,          wproj,  proj_b,  xr,  nullptr, x,    256, 256);
  bgemm_k<1><<<dim3(2, 392), 256, 0, stream>>>(H + TCsz,   wprojs, projs_b, xrs, nullptr, xsar, 256, 256);
  // 7. LN2 (bf16 out)
  ln_k<0><<<12544, 256, 0, stream>>>(xr,  ln2_g,  ln2_b,  y);
  ln_k<0><<<12544, 256, 0, stream>>>(xrs, ln2s_g, ln2s_b, ysb);
  // 8. MLP (MFMA), full M, hbuf bf16
  bgemm_k<2><<<dim3(8, 392), 256, 0, stream>>>(y,    wfc1,  fc1_b,  nullptr, hbuf, nullptr, 256, 1024);
  bgemm_k<3><<<dim3(2, 392), 256, 0, stream>>>(hbuf, wfc2,  fc2_b,  out,     nullptr, xr,  1024, 256);
  bgemm_k<2><<<dim3(8, 392), 256, 0, stream>>>(ysb,  wfc1s, fc1s_b, nullptr, hbuf, nullptr, 256, 1024);
  bgemm_k<3><<<dim3(2, 392), 256, 0, stream>>>(hbuf, wfc2s, fc2s_b, out + TCsz, nullptr, xrs, 1024, 256);
}

// Round 2
// 969.937 us; speedup vs baseline: 1.2275x; 1.0536x over previous
//
#include <hip/hip_runtime.h>
#include <hip/hip_bf16.h>
#include <cstdio>

typedef unsigned short ushort_t;
using bf16x8  = __attribute__((ext_vector_type(8))) __bf16;
using floatx4 = __attribute__((ext_vector_type(4))) float;

// Problem constants
constexpr int    kTokens = 50176;                       // B*nW*N = 16*64*49
constexpr size_t TCsz    = (size_t)kTokens * 256;       // 12,845,056 elements
constexpr float  kScale  = 0.17677669529663687f;        // 32^-0.5
// Padded score layout: per (win,head) pair, 49 rows x 56 cols (16B-aligned rows)
constexpr int    SPITCH  = 56;
constexpr size_t SPAIR   = 49 * 56;                     // 2744
constexpr size_t SBUFSZ  = (size_t)8192 * SPAIR;        // 22,478,848 halves per branch

__device__ __forceinline__ float bf2f(ushort_t u) {
  unsigned int x = (unsigned int)u << 16;
  return __uint_as_float(x);
}
__device__ __forceinline__ ushort_t f2bf(float f) {
  __hip_bfloat16 h = __float2bfloat16(f);
  return *(ushort_t*)&h;
}

// async global->LDS 16B per lane: LDS dest = wave-uniform base + lane*16
__device__ __forceinline__ void gl_lds16(const ushort_t* g, ushort_t* l) {
  __builtin_amdgcn_global_load_lds(
      (const __attribute__((address_space(1))) unsigned int*)g,
      (__attribute__((address_space(3))) unsigned int*)l, 16, 0, 0);
}

// ---------------- weight fp32 -> bf16 conversion ----------------
__global__ __launch_bounds__(256) void f2b_k(const float* __restrict__ src,
                                             ushort_t* __restrict__ dst, int n) {
  int i = blockIdx.x * 256 + threadIdx.x;
  if (i < n) dst[i] = f2bf(src[i]);
}

// ---------------- precompute rpb + shift-mask bias table ----------------
// bias[cls][head][i][j], cls = (wh==7?2:0)+(ww==7?1:0), 49x56 tile (pad cols = 0)
__global__ __launch_bounds__(256) void bias_k(const float* __restrict__ rpb,
                                              float* __restrict__ bias,
                                              ushort_t* __restrict__ guard) {
  const int cls = blockIdx.x >> 3, head = blockIdx.x & 7;
  const int wh7 = cls >> 1, ww7 = cls & 1;
  float* bp = bias + (size_t)blockIdx.x * SPAIR;
  for (int e = threadIdx.x; e < (int)SPAIR; e += 256) {
    const int i = e / SPITCH, j = e % SPITCH;
    float val = 0.0f;
    if (j < 49) {
      const int yi = i / 7, xi = i % 7, yj = j / 7, xj = j % 7;
      val = rpb[((yi - yj + 6) * 13 + (xi - xj + 6)) * 8 + head];
      const int li = (wh7 ? (yi < 4 ? 1 : 2) : 0) * 3 + (ww7 ? (xi < 4 ? 1 : 2) : 0);
      const int lj = (wh7 ? (yj < 4 ? 1 : 2) : 0) * 3 + (ww7 ? (xj < 4 ? 1 : 2) : 0);
      if (li != lj) val -= 100.0f;
    }
    bp[e] = val;
  }
  if (blockIdx.x == 0 && threadIdx.x < 64) guard[threadIdx.x] = 0;  // NaN guard past SB
}

// ---------------- LN (wave per token) + optional roll/window scatter -> bf16 ----------------
template <int SHIFTED>
__global__ __launch_bounds__(256) void ln_k(const float* __restrict__ x,
                                            const float* __restrict__ g,
                                            const float* __restrict__ b,
                                            ushort_t* __restrict__ yout) {
  const int wave = threadIdx.x >> 6, lane = threadIdx.x & 63;
  const int t = blockIdx.x * 4 + wave;
  size_t src;
  if (SHIFTED) {
    int bb = t / 3136, r = t % 3136;
    int wi = r / 49, n = r % 49;
    int hp = (wi >> 3) * 7 + n / 7;
    int wp = (wi & 7) * 7 + n % 7;
    int sh = hp + 3; if (sh >= 56) sh -= 56;
    int sw = wp + 3; if (sw >= 56) sw -= 56;
    src = ((size_t)bb * 3136 + sh * 56 + sw) * 256;
  } else {
    src = (size_t)t * 256;
  }
  const float4 v4 = *(const float4*)(x + src + lane * 4);
  float s  = v4.x + v4.y + v4.z + v4.w;
  float s2 = v4.x * v4.x + v4.y * v4.y + v4.z * v4.z + v4.w * v4.w;
#pragma unroll
  for (int off = 32; off > 0; off >>= 1) {
    s  += __shfl_xor(s,  off);
    s2 += __shfl_xor(s2, off);
  }
  const float mean = s * (1.0f / 256.0f);
  const float var  = s2 * (1.0f / 256.0f) - mean * mean;
  const float rstd = rsqrtf(var + 1e-5f);
  const float4 g4 = *(const float4*)(g + lane * 4);
  const float4 b4 = *(const float4*)(b + lane * 4);
  ushort4 o;
  o.x = f2bf((v4.x - mean) * rstd * g4.x + b4.x);
  o.y = f2bf((v4.y - mean) * rstd * g4.y + b4.y);
  o.z = f2bf((v4.z - mean) * rstd * g4.z + b4.z);
  o.w = f2bf((v4.w - mean) * rstd * g4.w + b4.w);
  *(ushort4*)(yout + (size_t)t * 256 + lane * 4) = o;
}

// ---------------- bf16 MFMA GEMM: out = A(M x K,bf16) @ W(N x K,bf16)^T ----------------
// 128x128 tile, BK=32, 4 waves. Staging via global_load_lds (linear LDS dest,
// inverse-XOR-swizzled global source); ds_read_b128 with matching XOR swizzle
// keyed by (row>>1)&3 -> conflict-free. Bijective XCD chunk swizzle on block id.
template <int MODE>
__global__ __launch_bounds__(256) void bgemm_k(const ushort_t* __restrict__ A,
                                               const ushort_t* __restrict__ W,
                                               const float* __restrict__ bias,
                                               float* __restrict__ outf,
                                               ushort_t* __restrict__ outb,
                                               const float* __restrict__ aux,
                                               int K, int Nc) {
  __shared__ __align__(16) ushort_t As[128 * 32];
  __shared__ __align__(16) ushort_t Bs[128 * 32];
  const int tid = threadIdx.x;
  const int nbx = gridDim.x;
  const int nwg = nbx * gridDim.y;
  int flat = blockIdx.y * nbx + blockIdx.x;
  {
    const int xcd = flat & 7, idx = flat >> 3;
    const int q8 = nwg >> 3, r8 = nwg & 7;
    flat = (xcd < r8 ? xcd * (q8 + 1) : r8 * (q8 + 1) + (xcd - r8) * q8) + idx;
  }
  const int m0 = (flat / nbx) * 128;
  const int n0 = (flat % nbx) * 128;
  const int lane = tid & 63, wv = tid >> 6;
  const int wm = (wv >> 1) * 64, wn = (wv & 1) * 64;
  const int l16 = lane & 15, quad = lane >> 4;

  // staging: row-within-64 = tid>>2, phys chunk = tid&3,
  // global chunk = (tid&3) ^ ((tid>>3)&3)   (swizzle key (row>>1)&3)
  const int srow = tid >> 2;
  const int gkc  = (tid & 3) ^ ((tid >> 3) & 3);
  const ushort_t* Ag0 = A + (size_t)(m0 + srow) * K + gkc * 8;
  const ushort_t* Ag1 = A + (size_t)(m0 + 64 + srow) * K + gkc * 8;
  const ushort_t* Wg0 = W + (size_t)(n0 + srow) * K + gkc * 8;
  const ushort_t* Wg1 = W + (size_t)(n0 + 64 + srow) * K + gkc * 8;
  ushort_t* AsW0 = As + wv * 512;          // rows [wv*16, wv*16+16)
  ushort_t* AsW1 = As + 2048 + wv * 512;   // rows [64+wv*16, ...)
  ushort_t* BsW0 = Bs + wv * 512;
  ushort_t* BsW1 = Bs + 2048 + wv * 512;

  const int kcq = quad ^ ((l16 >> 1) & 3);
  const int arA = (wm + l16) * 32 + kcq * 8;
  const int arB = (wn + l16) * 32 + kcq * 8;

  floatx4 acc[4][4] = {};
  for (int k0 = 0; k0 < K; k0 += 32) {
    gl_lds16(Ag0, AsW0);
    gl_lds16(Ag1, AsW1);
    gl_lds16(Wg0, BsW0);
    gl_lds16(Wg1, BsW1);
    Ag0 += 32; Ag1 += 32; Wg0 += 32; Wg1 += 32;
    __syncthreads();
    bf16x8 af[4], bfr[4];
#pragma unroll
    for (int t = 0; t < 4; ++t) {
      af[t]  = *(const bf16x8*)&As[arA + t * 512];
      bfr[t] = *(const bf16x8*)&Bs[arB + t * 512];
    }
#pragma unroll
    for (int mt = 0; mt < 4; ++mt)
#pragma unroll
      for (int nt = 0; nt < 4; ++nt)
        acc[mt][nt] = __builtin_amdgcn_mfma_f32_16x16x32_bf16(af[mt], bfr[nt], acc[mt][nt], 0, 0, 0);
    __syncthreads();
  }

  // C/D layout: col = lane&15, row = quad*4 + reg. Row-scatter bases hoisted.
  if (MODE == 0) {
    size_t rb[16];
#pragma unroll
    for (int mt = 0; mt < 4; ++mt) {
      int row = m0 + wm + mt * 16 + quad * 4;
      int wi = row / 49, n = row - wi * 49;
#pragma unroll
      for (int r = 0; r < 4; ++r) {
        rb[mt * 4 + r] = (size_t)wi * 12544 + (size_t)n * 32;
        if (++n == 49) { n = 0; ++wi; }
      }
    }
#pragma unroll
    for (int nt = 0; nt < 4; ++nt) {
      const int col = n0 + wn + nt * 16 + l16;
      const int which = col >> 8, head = (col >> 5) & 7, d = col & 31;
      const float bv = bias[col];
      const float sc = (which == 0) ? kScale : 1.0f;
      ushort_t* ob = outb + (size_t)which * TCsz + head * 1568 + d;
#pragma unroll
      for (int i = 0; i < 16; ++i)
        ob[rb[i]] = f2bf((acc[i >> 2][nt][i & 3] + bv) * sc);
    }
  } else if (MODE == 1) {
    size_t rb[16];
#pragma unroll
    for (int mt = 0; mt < 4; ++mt) {
#pragma unroll
      for (int r = 0; r < 4; ++r) {
        const int row = m0 + wm + mt * 16 + quad * 4 + r;
        const int wi = row / 49, n = row - wi * 49;
        const int b = wi >> 6, wl = wi & 63;
        int h = (wl >> 3) * 7 + n / 7 + 3; if (h >= 56) h -= 56;
        int w = (wl & 7) * 7 + n % 7 + 3; if (w >= 56) w -= 56;
        rb[mt * 4 + r] = ((size_t)(b * 3136 + h * 56 + w)) * 256;
      }
    }
#pragma unroll
    for (int nt = 0; nt < 4; ++nt) {
      const int col = n0 + wn + nt * 16 + l16;
      const float bv = bias[col];
#pragma unroll
      for (int i = 0; i < 16; ++i) {
        const size_t idx = rb[i] + col;
        outf[idx] = aux[idx] + acc[i >> 2][nt][i & 3] + bv;
      }
    }
  } else if (MODE == 2) {
    size_t rb[16];
#pragma unroll
    for (int mt = 0; mt < 4; ++mt)
#pragma unroll
      for (int r = 0; r < 4; ++r)
        rb[mt * 4 + r] = (size_t)(m0 + wm + mt * 16 + quad * 4 + r) * Nc;
#pragma unroll
    for (int nt = 0; nt < 4; ++nt) {
      const int col = n0 + wn + nt * 16 + l16;
      const float bv = bias[col];
#pragma unroll
      for (int i = 0; i < 16; ++i) {
        float val = acc[i >> 2][nt][i & 3] + bv;
        val = 0.5f * val * (1.0f + erff(val * 0.70710678118654752f));
        outb[rb[i] + col] = f2bf(val);
      }
    }
  } else {
    size_t rb[16];
#pragma unroll
    for (int mt = 0; mt < 4; ++mt)
#pragma unroll
      for (int r = 0; r < 4; ++r)
        rb[mt * 4 + r] = (size_t)(m0 + wm + mt * 16 + quad * 4 + r) * 256;
#pragma unroll
    for (int nt = 0; nt < 4; ++nt) {
      const int col = n0 + wn + nt * 16 + l16;
      const float bv = bias[col];
#pragma unroll
      for (int i = 0; i < 16; ++i) {
        const size_t idx = rb[i] + col;
        outf[idx] = aux[idx] + acc[i >> 2][nt][i & 3] + bv;
      }
    }
  }
}

// ---------------- MFMA scores: S = q@k^T + bias(cls,head), one wave per (win,head) ----
__global__ __launch_bounds__(256) void scores_mfma_k(const ushort_t* __restrict__ q,
                                                     const ushort_t* __restrict__ k,
                                                     const float* __restrict__ bias,
                                                     ushort_t* __restrict__ S) {
  const int tid = threadIdx.x, lane = tid & 63, wv = tid >> 6;
  const int pair = blockIdx.x * 4 + wv;        // 8192 pairs
  const int head = pair & 7, win = pair >> 3;
  const int l16 = lane & 15, quad = lane >> 4;
  const ushort_t* qb = q + (size_t)pair * 1568;
  const ushort_t* kb = k + (size_t)pair * 1568;
  bf16x8 af[4], bfr[4];
#pragma unroll
  for (int t = 0; t < 4; ++t) {
    af[t]  = *(const bf16x8*)(qb + (t * 16 + l16) * 32 + quad * 8);
    bfr[t] = *(const bf16x8*)(kb + (t * 16 + l16) * 32 + quad * 8);
  }
  floatx4 acc[4][4] = {};
#pragma unroll
  for (int mt = 0; mt < 4; ++mt)
#pragma unroll
    for (int nt = 0; nt < 4; ++nt)
      acc[mt][nt] = __builtin_amdgcn_mfma_f32_16x16x32_bf16(af[mt], bfr[nt], acc[mt][nt], 0, 0, 0);

  const int wl = win & 63;
  const int cls = (((wl >> 3) == 7) ? 2 : 0) + (((wl & 7) == 7) ? 1 : 0);
  const float* bp = bias + (size_t)(cls * 8 + head) * SPAIR;
  ushort_t* Sp = S + (size_t)pair * SPAIR;
#pragma unroll
  for (int nt = 0; nt < 4; ++nt) {
    const int col = nt * 16 + l16;
    if (col >= SPITCH) continue;
#pragma unroll
    for (int mt = 0; mt < 4; ++mt) {
#pragma unroll
      for (int r = 0; r < 4; ++r) {
        const int row = mt * 16 + quad * 4 + r;
        if (row >= 49) continue;
        const float val = (col < 49) ? acc[mt][nt][r] + bp[row * SPITCH + col] : 0.0f;
        Sp[row * SPITCH + col] = f2bf(val);
      }
    }
  }
}

// ---------------- head-fusion gate + softmax, chunked (window, 13-row) blocks ------------
__global__ __launch_bounds__(256) void fuse2_k(ushort_t* __restrict__ S,
                                               ushort_t* __restrict__ Ss,
                                               const float* __restrict__ fw,
                                               const float* __restrict__ fb) {
  __shared__ float s[8][637], ss[8][637];   // 13*49 = 637 ; 40.8 KB total
  __shared__ float fwl[64], fbl[8];
  const int w = blockIdx.x >> 2, ch = blockIdx.x & 3;
  const int n0 = ch * 13;
  const int rows = (n0 + 13 <= 49) ? 13 : (49 - n0);
  const int cnt = 8 * rows * 49;
  const int tid = threadIdx.x;
  if (tid < 64) fwl[tid] = fw[tid];
  if (tid < 8)  fbl[tid] = fb[tid];
  for (int t = tid; t < cnt; t += 256) {
    const int h = t / (rows * 49), rm = t % (rows * 49);
    const int r = rm / 49, c = rm - r * 49;
    const size_t gaddr = (size_t)(w * 8 + h) * SPAIR + (size_t)(n0 + r) * SPITCH + c;
    s[h][rm]  = bf2f(S[gaddr]);
    ss[h][rm] = bf2f(Ss[gaddr]);
  }
  __syncthreads();
  for (int p = tid; p < rows * 49; p += 256) {
    float d[8];
#pragma unroll
    for (int h = 0; h < 8; ++h) d[h] = ss[h][p] - s[h][p];
#pragma unroll
    for (int o = 0; o < 8; ++o) {
      float g = fbl[o];
#pragma unroll
      for (int h = 0; h < 8; ++h) g = fmaf(fwl[o * 8 + h], d[h], g);
      g = 1.0f / (1.0f + expf(-g));
      s[o][p] = s[o][p] + d[o] * g;
    }
  }
  __syncthreads();
  // softmax: one thread per (branch, head, row)
  if (tid < 16 * rows) {
    const int br = tid / (8 * rows);
    const int hr = tid % (8 * rows);
    const int h = hr / rows, r = hr % rows;
    float* row = (br ? ss[h] : s[h]) + r * 49;
    float mx = -1e30f;
    for (int m = 0; m < 49; ++m) mx = fmaxf(mx, row[m]);
    float sum = 0.0f;
    for (int m = 0; m < 49; ++m) { float e = expf(row[m] - mx); row[m] = e; sum += e; }
    const float inv = 1.0f / sum;
    for (int m = 0; m < 49; ++m) row[m] *= inv;
  }
  __syncthreads();
  for (int t = tid; t < cnt; t += 256) {
    const int h = t / (rows * 49), rm = t % (rows * 49);
    const int r = rm / 49, c = rm - r * 49;
    const size_t gaddr = (size_t)(w * 8 + h) * SPAIR + (size_t)(n0 + r) * SPITCH + c;
    S[gaddr]  = f2bf(s[h][rm]);
    Ss[gaddr] = f2bf(ss[h][rm]);
  }
}

// ---------------- MFMA PV: O = P @ V, one wave per (win,head) ----------------
__global__ __launch_bounds__(256) void pv_mfma_k(const ushort_t* __restrict__ P,
                                                 const ushort_t* __restrict__ v,
                                                 ushort_t* __restrict__ O) {
  __shared__ __align__(16) ushort_t vt[4][32][72];
  const int tid = threadIdx.x, lane = tid & 63, wv = tid >> 6;
  const int pair = blockIdx.x * 4 + wv;
  const int head = pair & 7, win = pair >> 3;
  const int l16 = lane & 15, quad = lane >> 4;
  const ushort_t* vb = v + (size_t)pair * 1568;
  // zero pad: m in [49,72) for all d  (32*23 = 736 elems)
  for (int e = lane; e < 736; e += 64) {
    const int d = e / 23, m = 49 + e % 23;
    vt[wv][d][m] = 0;
  }
  // transpose-stage V: vt[d][m] = v[m][d]
  for (int e = lane; e < 1568; e += 64) {
    vt[wv][e & 31][e >> 5] = vb[e];
  }
  __syncthreads();
  bf16x8 bfr[2][2];
#pragma unroll
  for (int nt = 0; nt < 2; ++nt)
#pragma unroll
    for (int ks = 0; ks < 2; ++ks)
      bfr[nt][ks] = *(const bf16x8*)&vt[wv][nt * 16 + l16][ks * 32 + quad * 8];

  const ushort_t* Pb = P + (size_t)pair * SPAIR;
  floatx4 acc[4][2] = {};
#pragma unroll
  for (int ks = 0; ks < 2; ++ks) {
#pragma unroll
    for (int mt = 0; mt < 4; ++mt) {
      const bf16x8 af = *(const bf16x8*)(Pb + (size_t)(mt * 16 + l16) * SPITCH + ks * 32 + quad * 8);
#pragma unroll
      for (int nt = 0; nt < 2; ++nt)
        acc[mt][nt] = __builtin_amdgcn_mfma_f32_16x16x32_bf16(af, bfr[nt][ks], acc[mt][nt], 0, 0, 0);
    }
  }
#pragma unroll
  for (int mt = 0; mt < 4; ++mt) {
#pragma unroll
    for (int r = 0; r < 4; ++r) {
      const int n = mt * 16 + quad * 4 + r;
      if (n >= 49) continue;
      const size_t base = ((size_t)(win * 49 + n)) * 256 + head * 32;
#pragma unroll
      for (int nt = 0; nt < 2; ++nt)
        O[base + nt * 16 + l16] = f2bf(acc[mt][nt][r]);
    }
  }
}

extern "C" void kernel_launch(void* const* d_in, const int* in_sizes, int n_in,
                              void* d_out, int out_size, void* d_ws, size_t ws_size,
                              hipStream_t stream) {
  if (n_in < 29) { fprintf(stderr, "kernel_launch: expected 29 inputs, got %d\n", n_in); return; }
  const float* x      = (const float*)d_in[0];
  const float* xsar   = (const float*)d_in[1];
  const float* ln1_g  = (const float*)d_in[2];
  const float* ln1_b  = (const float*)d_in[3];
  const float* ln1s_g = (const float*)d_in[4];
  const float* ln1s_b = (const float*)d_in[5];
  const float* qkv_w  = (const float*)d_in[6];
  const float* qkv_b  = (const float*)d_in[7];
  const float* qkvs_w = (const float*)d_in[8];
  const float* qkvs_b = (const float*)d_in[9];
  const float* rpb    = (const float*)d_in[10];
  const float* fuse_w = (const float*)d_in[11];
  const float* fuse_b = (const float*)d_in[12];
  const float* proj_w = (const float*)d_in[13];
  const float* proj_b = (const float*)d_in[14];
  const float* projs_w = (const float*)d_in[15];
  const float* projs_b = (const float*)d_in[16];
  const float* ln2_g  = (const float*)d_in[17];
  const float* ln2_b  = (const float*)d_in[18];
  const float* ln2s_g = (const float*)d_in[19];
  const float* ln2s_b = (const float*)d_in[20];
  const float* fc1_w  = (const float*)d_in[21];
  const float* fc1_b  = (const float*)d_in[22];
  const float* fc2_w  = (const float*)d_in[23];
  const float* fc2_b  = (const float*)d_in[24];
  const float* fc1s_w = (const float*)d_in[25];
  const float* fc1s_b = (const float*)d_in[26];
  const float* fc2s_w = (const float*)d_in[27];
  const float* fc2s_b = (const float*)d_in[28];
  float* out = (float*)d_out;
  float* ws  = (float*)d_ws;

  const size_t need = 8 * TCsz * sizeof(float);
  if (ws_size < need) {
    fprintf(stderr, "kernel_launch: ws_size %zu < needed %zu\n", ws_size, need);
    return;
  }

  // --- All-halves (bf16) workspace map; H unit = 1 bf16, 16*TCsz halves total ---
  ushort_t* H   = (ushort_t*)ws;
  ushort_t* xw  = H;
  ushort_t* xws = H + TCsz;
  ushort_t* q   = H + 2 * TCsz;   // q,k,v contiguous (which*TCsz offsets)
  ushort_t* qs  = H + 5 * TCsz;
  ushort_t* v_  = H + 4 * TCsz;
  ushort_t* vs  = H + 7 * TCsz;
  ushort_t* SA  = H + 8 * TCsz;
  ushort_t* SB  = SA + SBUFSZ;
  ushort_t* guard = SB + SBUFSZ;  // 64 halves zeroed (NaN guard for PV K-tail)
  float* xr  = ws + 6 * TCsz;
  float* xrs = ws + 7 * TCsz;
  ushort_t* y   = H + 2 * TCsz;
  ushort_t* ysb = H + 3 * TCsz;
  ushort_t* hbuf = H + 4 * TCsz;  // 4 TC halves: full M x 1024
  ushort_t* wb  = H + 12 * TCsz - 1572864;  // bf16 weights, below xr region
  float* biasbuf = (float*)(H + 12 * TCsz - 1572864 - 175616);  // 4*8*2744 fp32
  ushort_t* wqkv  = wb;
  ushort_t* wqkvs = wb + 196608;
  ushort_t* wproj = wb + 393216;
  ushort_t* wprojs= wb + 458752;
  ushort_t* wfc1  = wb + 524288;
  ushort_t* wfc1s = wb + 786432;
  ushort_t* wfc2  = wb + 1048576;
  ushort_t* wfc2s = wb + 1310720;

  // 0. convert weights to bf16 + precompute rpb/mask bias table
  f2b_k<<<768, 256, 0, stream>>>(qkv_w,  wqkv,  196608);
  f2b_k<<<768, 256, 0, stream>>>(qkvs_w, wqkvs, 196608);
  f2b_k<<<256, 256, 0, stream>>>(proj_w, wproj, 65536);
  f2b_k<<<256, 256, 0, stream>>>(projs_w,wprojs,65536);
  f2b_k<<<1024,256, 0, stream>>>(fc1_w,  wfc1,  262144);
  f2b_k<<<1024,256, 0, stream>>>(fc1s_w, wfc1s, 262144);
  f2b_k<<<1024,256, 0, stream>>>(fc2_w,  wfc2,  262144);
  f2b_k<<<1024,256, 0, stream>>>(fc2s_w, wfc2s, 262144);
  bias_k<<<32, 256, 0, stream>>>(rpb, biasbuf, guard);

  // 1. LN1 + shift + window partition (bf16 out), wave-per-token
  ln_k<1><<<12544, 256, 0, stream>>>(x,    ln1_g,  ln1_b,  xw);
  ln_k<1><<<12544, 256, 0, stream>>>(xsar, ln1s_g, ln1s_b, xws);
  // 2. QKV MFMA GEMM (q pre-scaled), scatter bf16 to (win,head,n,d)
  bgemm_k<0><<<dim3(6, 392), 256, 0, stream>>>(xw,  wqkv,  qkv_b,  nullptr, q,  nullptr, 256, 768);
  bgemm_k<0><<<dim3(6, 392), 256, 0, stream>>>(xws, wqkvs, qkvs_b, nullptr, qs, nullptr, 256, 768);
  // 3. MFMA scores + precomputed bias (bf16 out, padded 49x56)
  scores_mfma_k<<<2048, 256, 0, stream>>>(q,  q + TCsz,  biasbuf, SA);
  scores_mfma_k<<<2048, 256, 0, stream>>>(qs, qs + TCsz, biasbuf, SB);
  // 4. gate fusion + softmax (in place, chunked; pad cols preserved as 0)
  fuse2_k<<<4096, 256, 0, stream>>>(SA, SB, fuse_w, fuse_b);
  // 5. MFMA P @ V -> bf16 token-major
  pv_mfma_k<<<2048, 256, 0, stream>>>(SA, v_, H);          // O -> xw slot
  pv_mfma_k<<<2048, 256, 0, stream>>>(SB, vs, H + TCsz);   // Os -> xws slot
  // 6. proj MFMA + window-reverse + roll(+3) + residual -> fp32 xr
  bgemm_k<1><<<dim3(2, 392), 256, 0, stream>>>(H,          wproj,  proj_b,  xr,  nullptr, x,    256, 256);
  bgemm_k<1><<<dim3(2, 392), 256, 0, stream>>>(H + TCsz,   wprojs, projs_b, xrs, nullptr, xsar, 256, 256);
  // 7. LN2 (bf16 out)
  ln_k<0><<<12544, 256, 0, stream>>>(xr,  ln2_g,  ln2_b,  y);
  ln_k<0><<<12544, 256, 0, stream>>>(xrs, ln2s_g, ln2s_b, ysb);
  // 8. MLP (MFMA), full M, hbuf bf16
  bgemm_k<2><<<dim3(8, 392), 256, 0, stream>>>(y,    wfc1,  fc1_b,  nullptr, hbuf, nullptr, 256, 1024);
  bgemm_k<3><<<dim3(2, 392), 256, 0, stream>>>(hbuf, wfc2,  fc2_b,  out,     nullptr, xr,  1024, 256);
  bgemm_k<2><<<dim3(8, 392), 256, 0, stream>>>(ysb,  wfc1s, fc1s_b, nullptr, hbuf, nullptr, 256, 1024);
  bgemm_k<3><<<dim3(2, 392), 256, 0, stream>>>(hbuf, wfc2s, fc2s_b, out + TCsz, nullptr, xrs, 1024, 256);
}